// Round 11
// baseline (535.537 us; speedup 1.0000x reference)
//
#include <hip/hip_runtime.h>
#include <math.h>

#define B_ 16
#define A_ 32
#define G_ 512
#define S_ 4096
#define M_ 8
#define BS_ 65536
#define KC_ 640      // concat K: 512 normed + 100 OH + 28 pad
#define NG_ 1536

typedef _Float16 half8 __attribute__((ext_vector_type(8)));
typedef _Float16 half4v __attribute__((ext_vector_type(4)));
typedef _Float16 half2v __attribute__((ext_vector_type(2)));
typedef float floatx4 __attribute__((ext_vector_type(4)));

typedef const __attribute__((address_space(1))) void* gas_t;
typedef __attribute__((address_space(3))) void* las_t;

// ---------------- helpers ----------------
__device__ __forceinline__ float wave_sum_f(float v){
#pragma unroll
  for (int o = 32; o > 0; o >>= 1) v += __shfl_xor(v, o);
  return v;
}
__device__ __forceinline__ float wave_max_f(float v){
#pragma unroll
  for (int o = 32; o > 0; o >>= 1) v = fmaxf(v, __shfl_xor(v, o));
  return v;
}
__device__ __forceinline__ float sigmoidf_(float x){ return 1.f/(1.f+__expf(-x)); }
__device__ __forceinline__ float tanhf_(float x){ return 1.f - 2.f/(__expf(2.f*x)+1.f); }

// ---------------- K0a: fp32 -> fp16 convert, 3 G*G matrices ----------------
__global__ __launch_bounds__(256) void k_cvt3(const float* __restrict__ s0,
                                              const float* __restrict__ s1,
                                              const float* __restrict__ s2,
                                              _Float16* __restrict__ d){
  const float* s = (blockIdx.y == 0) ? s0 : (blockIdx.y == 1) ? s1 : s2;
  int i = (blockIdx.x*256 + threadIdx.x)*4;
  if (i >= G_*G_) return;
  float4 v = *(const float4*)(s+i);
  half4v o; o[0]=(_Float16)v.x; o[1]=(_Float16)v.y; o[2]=(_Float16)v.z; o[3]=(_Float16)v.w;
  *(half4v*)(d + (size_t)blockIdx.y*G_*G_ + i) = o;
}

// ---------------- K0b: build Wcat[1536][640] = [W_hh | W_ih | 0] ------------
__global__ __launch_bounds__(64) void k_buildw(const float* __restrict__ Whh,
                                               const float* __restrict__ Wih,
                                               _Float16* __restrict__ Wcat){
  int j = blockIdx.x;
  for (int p = threadIdx.x; p < KC_; p += 64){
    float v = 0.f;
    if (p < 512) v = Whh[(size_t)j*512 + p];
    else if (p < 612) v = Wih[(size_t)j*100 + (p - 512)];
    Wcat[(size_t)j*KC_ + p] = (_Float16)v;
  }
}

// ---------------- K1: MFMA prep — swvs GEMM + LN + counts + OH --------------
__global__ __launch_bounds__(256) void k_prep_mfma(
    const float* __restrict__ vf, const float* __restrict__ mask,
    const float* __restrict__ eoh, const float* __restrict__ subs,
    const float* __restrict__ ln_g, const float* __restrict__ ln_b,
    _Float16* __restrict__ Abuf){
  __shared__ _Float16 s_mvfT[G_*A_];   // [g][a], masked vf, 32 KB
  __shared__ _Float16 s_sm[128*A_];    // [s][a], raw subs, 8 KB
  __shared__ float s_m[A_];
  __shared__ float s_e[A_*5];
  __shared__ float s_ssum[128];
  __shared__ float s_red1[2][4][16];
  __shared__ float s_red2[2][4][16];
  int tid = threadIdx.x;
  int bx = blockIdx.x, b = blockIdx.y;
  int lane = tid & 63, w = tid >> 6;
  int q = lane >> 4, l15 = lane & 15;
  size_t row0 = (size_t)b*S_ + (size_t)bx*128;
  if (tid < A_)   s_m[tid] = mask[b*A_ + tid];
  if (tid < A_*5) s_e[tid] = eoh[b*A_*5 + tid];
  __syncthreads();
  {
    int p = tid & 15, gseg = tid >> 4;
    float mk0 = s_m[2*p], mk1 = s_m[2*p+1];
    const float* v0 = vf + ((size_t)b*A_ + 2*p)*G_ + gseg*32;
    const float* v1 = v0 + G_;
#pragma unroll
    for (int i = 0; i < 32; i += 4){
      float4 a = *(const float4*)(v0 + i);
      float4 c = *(const float4*)(v1 + i);
      float av[4] = {a.x, a.y, a.z, a.w};
      float cv[4] = {c.x, c.y, c.z, c.w};
#pragma unroll
      for (int j = 0; j < 4; ++j){
        half2v h; h[0] = (_Float16)(av[j]*mk0); h[1] = (_Float16)(cv[j]*mk1);
        *(half2v*)(s_mvfT + (gseg*32 + i + j)*A_ + 2*p) = h;
      }
    }
  }
  {
    int s = tid >> 1, hh = tid & 1;
    const float* sp = subs + (row0 + s)*A_ + hh*16;
    _Float16* dst = s_sm + s*A_ + hh*16;
#pragma unroll
    for (int i = 0; i < 16; i += 4){
      float4 v = *(const float4*)(sp + i);
      half4v h; h[0]=(_Float16)v.x; h[1]=(_Float16)v.y; h[2]=(_Float16)v.z; h[3]=(_Float16)v.w;
      *(half4v*)(dst + i) = h;
    }
  }
  __syncthreads();
  if (tid < 128){
    int s = tid;
    float ssum = 0.f, c0=0.f, c1=0.f, c2=0.f, c3=0.f, c4=0.f;
#pragma unroll
    for (int a = 0; a < A_; ++a){
      float v = (float)s_sm[s*A_ + a];
      ssum += v * s_m[a];
      c0 += v * s_e[a*5+0]; c1 += v * s_e[a*5+1]; c2 += v * s_e[a*5+2];
      c3 += v * s_e[a*5+3]; c4 += v * s_e[a*5+4];
    }
    int cc[5];
    cc[0] = min(max((int)(c0+0.5f),0),19); cc[1] = min(max((int)(c1+0.5f),0),19);
    cc[2] = min(max((int)(c2+0.5f),0),19); cc[3] = min(max((int)(c3+0.5f),0),19);
    cc[4] = min(max((int)(c4+0.5f),0),19);
    s_ssum[s] = ssum;
    _Float16* dst = Abuf + (row0 + s)*KC_ + 512;
#pragma unroll
    for (int t = 0; t < 16; ++t){
      half8 hv;
#pragma unroll
      for (int u = 0; u < 8; ++u){
        int k = t*8 + u;
        float v = 0.f;
        if (k < 100){ int f = k/20, l = k - f*20; v = (l <= cc[f]) ? 1.f : 0.f; }
        hv[u] = (_Float16)v;
      }
      *(half8*)(dst + t*8) = hv;
    }
  }
  half8 bf[8]; float lng[8], lnb[8];
#pragma unroll
  for (int t = 0; t < 8; ++t){
    int g = w*128 + t*16 + l15;
    bf[t] = *(const half8*)(s_mvfT + g*A_ + q*8);
    lng[t] = ln_g[g]; lnb[t] = ln_b[g];
  }
  __syncthreads();
  for (int gi = 0; gi < 8; ++gi){
    half8 af = *(const half8*)(s_sm + (gi*16 + l15)*A_ + q*8);
    floatx4 c[8];
#pragma unroll
    for (int t = 0; t < 8; ++t){
      floatx4 z = {0.f, 0.f, 0.f, 0.f};
      c[t] = __builtin_amdgcn_mfma_f32_16x16x32_f16(af, bf[t], z, 0, 0, 0);
    }
    float p1[4] = {0.f,0.f,0.f,0.f}, p2[4] = {0.f,0.f,0.f,0.f};
#pragma unroll
    for (int t = 0; t < 8; ++t)
#pragma unroll
      for (int r = 0; r < 4; ++r){ float v = c[t][r]; p1[r] += v; p2[r] += v*v; }
#pragma unroll
    for (int off = 1; off < 16; off <<= 1)
#pragma unroll
      for (int r = 0; r < 4; ++r){
        p1[r] += __shfl_xor(p1[r], off);
        p2[r] += __shfl_xor(p2[r], off);
      }
    int gb = gi & 1;
    if (l15 == 0){
#pragma unroll
      for (int r = 0; r < 4; ++r){ s_red1[gb][w][q*4+r] = p1[r]; s_red2[gb][w][q*4+r] = p2[r]; }
    }
    __syncthreads();   // single barrier per gi (double-buffered s_red)
#pragma unroll
    for (int r = 0; r < 4; ++r){
      int sl = gi*16 + q*4 + r;
      int rr = q*4 + r;
      float t1 = s_red1[gb][0][rr] + s_red1[gb][1][rr] + s_red1[gb][2][rr] + s_red1[gb][3][rr];
      float t2 = s_red2[gb][0][rr] + s_red2[gb][1][rr] + s_red2[gb][2][rr] + s_red2[gb][3][rr];
      float inv = 1.f/(s_ssum[sl] + 1e-4f);
      float mu = t1*inv*(1.f/512.f);
      float var = t2*inv*inv*(1.f/512.f) - mu*mu;
      float rs = rsqrtf(var + 1e-5f);
      _Float16* orow = Abuf + (row0 + sl)*KC_;
#pragma unroll
      for (int t = 0; t < 8; ++t){
        float o = (c[t][r]*inv - mu)*rs*lng[t] + lnb[t];
        orow[w*128 + t*16 + l15] = (_Float16)o;
      }
    }
  }
}

// ---------------- K2: fused (gh+gi) GEMM (3 gates) + GRU elementwise --------
// (unchanged from r10 — measured plateau for this structure)
__global__ __launch_bounds__(512) void k_gru_fused(
    const _Float16* __restrict__ Abuf, const _Float16* __restrict__ Wcat,
    const float* __restrict__ bih, const float* __restrict__ bhh,
    _Float16* __restrict__ H){
  __shared__ _Float16 smA[128*32];   // 8 KB
  __shared__ _Float16 smB[192*32];   // 12 KB
  int tid = threadIdx.x;
  int lane = tid & 63, wvid = tid >> 6;      // 8 waves
  int wm = wvid & 1, wn = wvid >> 1;
  int q = lane >> 4, l15 = lane & 15;
  int mt = blockIdx.x*64 + (blockIdx.y >> 3);
  int dt = blockIdx.y & 7;
  int m0 = mt*128, n0 = dt*64;
  floatx4 acc[3][4] = {};
  floatx4 accNI[4] = {};
  int offA[4], offB[3];
#pragma unroll
  for (int i = 0; i < 4; ++i){
    int r = wm*64 + i*16 + l15;
    offA[i] = (r*4 + (q ^ ((r>>2)&3)))*8;
  }
#pragma unroll
  for (int g = 0; g < 3; ++g){
    int rb = g*64 + wn*16 + l15;
    offB[g] = (rb*4 + (q ^ ((rb>>2)&3)))*8;
  }
  const _Float16* gA;
  {
    int u = wvid*64 + lane;
    int r = u >> 2, c = (u & 3) ^ ((r >> 2) & 3);
    gA = Abuf + (size_t)(m0 + r)*KC_ + c*8;
  }
  const _Float16* gB0;
  {
    int u = wvid*64 + lane;
    int rb = u >> 2, c = (u & 3) ^ ((rb >> 2) & 3);
    int grow = (rb >> 6)*512 + n0 + (rb & 63);
    gB0 = Wcat + (size_t)grow*KC_ + c*8;
  }
  const _Float16* gB1 = nullptr;
  if (wvid < 4){
    int u = (8 + wvid)*64 + lane;
    int rb = u >> 2, c = (u & 3) ^ ((rb >> 2) & 3);
    int grow = (rb >> 6)*512 + n0 + (rb & 63);
    gB1 = Wcat + (size_t)grow*KC_ + c*8;
  }
  for (int kc = 0; kc < 512; kc += 32){
    __builtin_amdgcn_global_load_lds((gas_t)(gA + kc), (las_t)(smA + wvid*512), 16, 0, 0);
    __builtin_amdgcn_global_load_lds((gas_t)(gB0 + kc), (las_t)(smB + wvid*512), 16, 0, 0);
    if (wvid < 4)
      __builtin_amdgcn_global_load_lds((gas_t)(gB1 + kc), (las_t)(smB + (8+wvid)*512), 16, 0, 0);
    __syncthreads();
    half8 af[4], bfv[3];
#pragma unroll
    for (int i = 0; i < 4; ++i) af[i] = *(const half8*)(smA + offA[i]);
#pragma unroll
    for (int g = 0; g < 3; ++g) bfv[g] = *(const half8*)(smB + offB[g]);
#pragma unroll
    for (int g = 0; g < 3; ++g)
#pragma unroll
      for (int i = 0; i < 4; ++i)
        acc[g][i] = __builtin_amdgcn_mfma_f32_16x16x32_f16(af[i], bfv[g], acc[g][i], 0, 0, 0);
    __syncthreads();
  }
  for (int kc = 512; kc < KC_; kc += 32){
    __builtin_amdgcn_global_load_lds((gas_t)(gA + kc), (las_t)(smA + wvid*512), 16, 0, 0);
    __builtin_amdgcn_global_load_lds((gas_t)(gB0 + kc), (las_t)(smB + wvid*512), 16, 0, 0);
    if (wvid < 4)
      __builtin_amdgcn_global_load_lds((gas_t)(gB1 + kc), (las_t)(smB + (8+wvid)*512), 16, 0, 0);
    __syncthreads();
    half8 af[4], bfv[3];
#pragma unroll
    for (int i = 0; i < 4; ++i) af[i] = *(const half8*)(smA + offA[i]);
#pragma unroll
    for (int g = 0; g < 3; ++g) bfv[g] = *(const half8*)(smB + offB[g]);
#pragma unroll
    for (int i = 0; i < 4; ++i){
      acc[0][i] = __builtin_amdgcn_mfma_f32_16x16x32_f16(af[i], bfv[0], acc[0][i], 0, 0, 0);
      acc[1][i] = __builtin_amdgcn_mfma_f32_16x16x32_f16(af[i], bfv[1], acc[1][i], 0, 0, 0);
      accNI[i]  = __builtin_amdgcn_mfma_f32_16x16x32_f16(af[i], bfv[2], accNI[i], 0, 0, 0);
    }
    __syncthreads();
  }
  int d = n0 + wn*16 + l15;
  float br  = bih[d] + bhh[d];
  float bz  = bih[512+d] + bhh[512+d];
  float bnh = bhh[1024+d];
  float bni = bih[1024+d];
#pragma unroll
  for (int i = 0; i < 4; ++i){
#pragma unroll
    for (int r = 0; r < 4; ++r){
      int m = m0 + wm*64 + i*16 + q*4 + r;
      float gr  = acc[0][i][r] + br;
      float gz  = acc[1][i][r] + bz;
      float hn  = acc[2][i][r] + bnh;
      float in_ = accNI[i][r] + bni;
      float rrv = sigmoidf_(gr);
      float zz  = sigmoidf_(gz);
      float nn  = tanhf_(in_ + rrv*hn);
      float hp  = (float)Abuf[(size_t)m*KC_ + d];
      H[(size_t)m*G_ + d] = (_Float16)((1.f-zz)*nn + zz*hp);
    }
  }
}

// ---------------- K3: FF fp16 MFMA GEMM, BK=64  Out = relu(A@W^T+b) ---------
// K=512, N=512. grid (8, 256): xcd=bx; mt = bx*64 + (by>>2), nt = by&3.
// LDS 2x16KB; 8 K-iters, 32 MFMA per barrier per wave. Swizzle c^(r&7).
__global__ __launch_bounds__(256) void k_gemm64(
    const _Float16* __restrict__ A, const _Float16* __restrict__ W,
    const float* __restrict__ bias, _Float16* __restrict__ Out){
  __shared__ _Float16 smA[128*64];
  __shared__ _Float16 smB[128*64];
  int tid = threadIdx.x;
  int lane = tid & 63, wvid = tid >> 6;
  int wm = wvid & 1, wn = wvid >> 1;
  int q = lane >> 4, l15 = lane & 15;
  int mt = blockIdx.x*64 + (blockIdx.y >> 2);
  int nt = blockIdx.y & 3;
  int m0 = mt*128, n0 = nt*128;
  floatx4 acc[4][4] = {};
  int offA[2][4], offB[2][4];
#pragma unroll
  for (int s = 0; s < 2; ++s)
#pragma unroll
    for (int i = 0; i < 4; ++i){
      int r = wm*64 + i*16 + l15;
      offA[s][i] = r*64 + (((s*4+q) ^ (r&7))*8);
      int rb = wn*64 + i*16 + l15;
      offB[s][i] = rb*64 + (((s*4+q) ^ (rb&7))*8);
    }
  const _Float16 *gA[4], *gB[4]; int so[4];
#pragma unroll
  for (int t = 0; t < 4; ++t){
    int seg = wvid*4 + t;
    int u = seg*64 + lane;
    int r = u >> 3, c = (u & 7) ^ (r & 7);
    so[t] = seg*512;
    gA[t] = A + (size_t)(m0 + r)*G_ + c*8;
    gB[t] = W + (size_t)(n0 + r)*G_ + c*8;
  }
  for (int kc = 0; kc < G_; kc += 64){
#pragma unroll
    for (int t = 0; t < 4; ++t){
      __builtin_amdgcn_global_load_lds((gas_t)(gA[t] + kc), (las_t)(smA + so[t]), 16, 0, 0);
      __builtin_amdgcn_global_load_lds((gas_t)(gB[t] + kc), (las_t)(smB + so[t]), 16, 0, 0);
    }
    __syncthreads();
#pragma unroll
    for (int s = 0; s < 2; ++s){
      half8 af[4], bfv[4];
#pragma unroll
      for (int i = 0; i < 4; ++i) af[i] = *(const half8*)(smA + offA[s][i]);
#pragma unroll
      for (int j = 0; j < 4; ++j) bfv[j] = *(const half8*)(smB + offB[s][j]);
#pragma unroll
      for (int i = 0; i < 4; ++i)
#pragma unroll
        for (int j = 0; j < 4; ++j)
          acc[i][j] = __builtin_amdgcn_mfma_f32_16x16x32_f16(af[i], bfv[j], acc[i][j], 0, 0, 0);
    }
    __syncthreads();
  }
#pragma unroll
  for (int j = 0; j < 4; ++j){
    int n = n0 + wn*64 + j*16 + l15;
    float bv = bias[n];
#pragma unroll
    for (int i = 0; i < 4; ++i){
#pragma unroll
      for (int r = 0; r < 4; ++r){
        int m = m0 + wm*64 + i*16 + q*4 + r;
        Out[(size_t)m*G_ + n] = (_Float16)fmaxf(acc[i][j][r] + bv, 0.f);
      }
    }
  }
}

// ---------------- K3b: FF3 GEMM (BK=64) + LN/score partials -----------------
// Instead of writing x3: per row partials P1=Σx, P2=Σx², P3=Σ(g·Ws)·x over
// this block's 128 cols -> Pbuf[m][nt][3]. x3 is never materialized.
__global__ __launch_bounds__(256) void k_ff3_fin(
    const _Float16* __restrict__ A, const _Float16* __restrict__ W,
    const float* __restrict__ bias, const float* __restrict__ ln_pre_g,
    const float* __restrict__ Ws, float* __restrict__ Pbuf){
  __shared__ _Float16 smA[128*64];
  __shared__ _Float16 smB[128*64];
  __shared__ float sP[2][64][2][3];
  int tid = threadIdx.x;
  int lane = tid & 63, wvid = tid >> 6;
  int wm = wvid & 1, wn = wvid >> 1;
  int q = lane >> 4, l15 = lane & 15;
  int mt = blockIdx.x*64 + (blockIdx.y >> 2);
  int nt = blockIdx.y & 3;
  int m0 = mt*128, n0 = nt*128;
  floatx4 acc[4][4] = {};
  int offA[2][4], offB[2][4];
#pragma unroll
  for (int s = 0; s < 2; ++s)
#pragma unroll
    for (int i = 0; i < 4; ++i){
      int r = wm*64 + i*16 + l15;
      offA[s][i] = r*64 + (((s*4+q) ^ (r&7))*8);
      int rb = wn*64 + i*16 + l15;
      offB[s][i] = rb*64 + (((s*4+q) ^ (rb&7))*8);
    }
  const _Float16 *gA[4], *gB[4]; int so[4];
#pragma unroll
  for (int t = 0; t < 4; ++t){
    int seg = wvid*4 + t;
    int u = seg*64 + lane;
    int r = u >> 3, c = (u & 7) ^ (r & 7);
    so[t] = seg*512;
    gA[t] = A + (size_t)(m0 + r)*G_ + c*8;
    gB[t] = W + (size_t)(n0 + r)*G_ + c*8;
  }
  for (int kc = 0; kc < G_; kc += 64){
#pragma unroll
    for (int t = 0; t < 4; ++t){
      __builtin_amdgcn_global_load_lds((gas_t)(gA[t] + kc), (las_t)(smA + so[t]), 16, 0, 0);
      __builtin_amdgcn_global_load_lds((gas_t)(gB[t] + kc), (las_t)(smB + so[t]), 16, 0, 0);
    }
    __syncthreads();
#pragma unroll
    for (int s = 0; s < 2; ++s){
      half8 af[4], bfv[4];
#pragma unroll
      for (int i = 0; i < 4; ++i) af[i] = *(const half8*)(smA + offA[s][i]);
#pragma unroll
      for (int j = 0; j < 4; ++j) bfv[j] = *(const half8*)(smB + offB[s][j]);
#pragma unroll
      for (int i = 0; i < 4; ++i)
#pragma unroll
        for (int j = 0; j < 4; ++j)
          acc[i][j] = __builtin_amdgcn_mfma_f32_16x16x32_f16(af[i], bfv[j], acc[i][j], 0, 0, 0);
    }
    __syncthreads();
  }
  // epilogue: per-row partials
  float gws[4], bv4[4];
#pragma unroll
  for (int j = 0; j < 4; ++j){
    int n = n0 + wn*64 + j*16 + l15;
    gws[j] = ln_pre_g[n]*Ws[n];
    bv4[j] = bias[n];
  }
#pragma unroll
  for (int i = 0; i < 4; ++i){
#pragma unroll
    for (int r = 0; r < 4; ++r){
      float p1 = 0.f, p2 = 0.f, p3 = 0.f;
#pragma unroll
      for (int j = 0; j < 4; ++j){
        float x = fmaxf(acc[i][j][r] + bv4[j], 0.f);
        p1 += x; p2 += x*x; p3 += gws[j]*x;
      }
#pragma unroll
      for (int off = 1; off < 16; off <<= 1){
        p1 += __shfl_xor(p1, off);
        p2 += __shfl_xor(p2, off);
        p3 += __shfl_xor(p3, off);
      }
      if (l15 == 0){
        int rl = i*16 + q*4 + r;
        sP[wm][rl][wn][0] = p1; sP[wm][rl][wn][1] = p2; sP[wm][rl][wn][2] = p3;
      }
    }
  }
  __syncthreads();
  if (tid < 128){
    int wmi = tid >> 6, rl = tid & 63;
    int m = m0 + wmi*64 + rl;
    float* dst = Pbuf + ((size_t)m*4 + nt)*3;
    dst[0] = sP[wmi][rl][0][0] + sP[wmi][rl][1][0];
    dst[1] = sP[wmi][rl][0][1] + sP[wmi][rl][1][1];
    dst[2] = sP[wmi][rl][0][2] + sP[wmi][rl][1][2];
  }
}

// ---------------- K4: finish scores from partials ---------------------------
// score = rs*(P3 - mu*C1) + C2 + bs, C1=Σ g·Ws, C2=Σ b·Ws.
__global__ __launch_bounds__(256) void k_score_fin(
    const float* __restrict__ Pbuf, const float* __restrict__ g,
    const float* __restrict__ bta, const float* __restrict__ Ws,
    const float* __restrict__ bs, float* __restrict__ scores){
  __shared__ float red[8];
  int tid = threadIdx.x, lane = tid & 63, wv = tid >> 6;
  int i0 = tid*2;
  float c1p = g[i0]*Ws[i0] + g[i0+1]*Ws[i0+1];
  float c2p = bta[i0]*Ws[i0] + bta[i0+1]*Ws[i0+1];
  c1p = wave_sum_f(c1p); c2p = wave_sum_f(c2p);
  if (lane == 0){ red[wv] = c1p; red[4+wv] = c2p; }
  __syncthreads();
  float c1 = red[0]+red[1]+red[2]+red[3];
  float c2 = red[4]+red[5]+red[6]+red[7] + bs[0];
  size_t row = (size_t)blockIdx.x*256 + tid;
  const float* p = Pbuf + row*12;
  float4 a  = *(const float4*)p;
  float4 b4 = *(const float4*)(p+4);
  float4 c4 = *(const float4*)(p+8);
  float P1 = a.x + a.w + b4.z + c4.y;
  float P2 = a.y + b4.x + b4.w + c4.z;
  float P3 = a.z + b4.y + c4.x + c4.w;
  float mu = P1*(1.f/512.f);
  float var = P2*(1.f/512.f) - mu*mu;
  float rs = rsqrtf(var + 1e-5f);
  scores[row] = rs*(P3 - mu*c1) + c2;
}

// ---------------- K5: softmax over S per batch ------------------------------
__global__ __launch_bounds__(256) void k_softmax(
    const float* __restrict__ scores, float* __restrict__ probs){
  __shared__ float red[4];
  int b = blockIdx.x, tid = threadIdx.x, lane = tid & 63, wv = tid >> 6;
  const float* sp = scores + (size_t)b*S_;
  float mx = -1e30f;
  for (int i = tid; i < S_; i += 256) mx = fmaxf(mx, sp[i]);
  mx = wave_max_f(mx);
  if (lane == 0) red[wv] = mx;
  __syncthreads();
  mx = fmaxf(fmaxf(red[0], red[1]), fmaxf(red[2], red[3]));
  __syncthreads();
  float sum = 0.f;
  for (int i = tid; i < S_; i += 256) sum += __expf(sp[i]-mx);
  sum = wave_sum_f(sum);
  if (lane == 0) red[wv] = sum;
  __syncthreads();
  sum = red[0]+red[1]+red[2]+red[3];
  float inv = 1.f/sum;
  for (int i = tid; i < S_; i += 256)
    probs[(size_t)b*S_ + i] = __expf(sp[i]-mx)*inv;
}

// ---------------- K6: spectrum scatter --------------------------------------
__global__ __launch_bounds__(256) void k_spect(
    const float* __restrict__ peaks, const float* __restrict__ probs,
    float* __restrict__ spect){
  __shared__ float bins[512];
  int b = blockIdx.x, tid = threadIdx.x;
  bins[tid] = 0.f; bins[tid+256] = 0.f;
  __syncthreads();
  for (int i = tid; i < S_*M_; i += 256){
    int s = i >> 3, m = i & 7;
    const float* pk = peaks + (((size_t)b*S_ + s)*M_ + m)*2;
    float mass = pk[0], inten = pk[1];
    float p = probs[(size_t)b*S_ + s];
    int bin = (int)rintf(mass);
    bin = min(max(bin, 0), 511);
    atomicAdd(&bins[bin], inten*p);
  }
  __syncthreads();
  spect[(size_t)b*512 + tid]       = bins[tid];
  spect[(size_t)b*512 + tid + 256] = bins[tid+256];
}

// ---------------- launcher --------------------------------------------------
extern "C" void kernel_launch(void* const* d_in, const int* in_sizes, int n_in,
                              void* d_out, int out_size, void* d_ws, size_t ws_size,
                              hipStream_t stream) {
  const float* vf       = (const float*)d_in[0];
  const float* mask     = (const float*)d_in[1];
  const float* eoh      = (const float*)d_in[2];
  const float* subs     = (const float*)d_in[4];
  const float* peaks    = (const float*)d_in[5];
  const float* ln_sub_g = (const float*)d_in[6];
  const float* ln_sub_b = (const float*)d_in[7];
  const float* W_ih     = (const float*)d_in[8];
  const float* W_hh     = (const float*)d_in[9];
  const float* b_ih     = (const float*)d_in[10];
  const float* b_hh     = (const float*)d_in[11];
  const float* W1       = (const float*)d_in[12];
  const float* b1       = (const float*)d_in[13];
  const float* W2a      = (const float*)d_in[14];
  const float* b2a      = (const float*)d_in[15];
  const float* W2b      = (const float*)d_in[16];
  const float* b2b      = (const float*)d_in[17];
  const float* ln_pre_g = (const float*)d_in[18];
  const float* ln_pre_b = (const float*)d_in[19];
  const float* Ws       = (const float*)d_in[20];
  const float* bs       = (const float*)d_in[21];
  float* out = (float*)d_out;            // [0,8192) spect, [8192,73728) probs
  float* probs_out = out + (size_t)B_*512;

  // workspace carve — ~158 MB (ws >= ~206 MB proven)
  char* w = (char*)d_ws;
  float* scores = (float*)w;     w += (size_t)BS_*4;
  float* Pbuf   = (float*)w;     w += (size_t)BS_*12*4;        // 3 MB
  _Float16* Wcat = (_Float16*)w; w += (size_t)NG_*KC_*2;       // ~2 MB
  _Float16* W1h  = (_Float16*)w; w += (size_t)G_*G_*2;
  _Float16* W2ah = (_Float16*)w; w += (size_t)G_*G_*2;
  _Float16* W2bh = (_Float16*)w; w += (size_t)G_*G_*2;
  _Float16* Abuf = (_Float16*)w; w += (size_t)BS_*KC_*2;       // 84 MB
  _Float16* bufh0 = (_Float16*)w;                              // 67 MB (H)
  _Float16* bufh1 = Abuf;        // x1 reuses A region (84 >= 67 MB)

  k_cvt3<<<dim3((G_*G_/4+255)/256, 3), 256, 0, stream>>>(W1, W2a, W2b, W1h);
  k_buildw<<<NG_, 64, 0, stream>>>(W_hh, W_ih, Wcat);
  k_prep_mfma<<<dim3(S_/128, B_), 256, 0, stream>>>(vf, mask, eoh, subs,
                                                    ln_sub_g, ln_sub_b, Abuf);
  k_gru_fused<<<dim3(8, 512), 512, 0, stream>>>(Abuf, Wcat, b_ih, b_hh, bufh0);
  k_gemm64<<<dim3(8, 256), 256, 0, stream>>>(bufh0, W1h,  b1,  bufh1);   // x1
  k_gemm64<<<dim3(8, 256), 256, 0, stream>>>(bufh1, W2ah, b2a, bufh0);   // x2
  k_ff3_fin<<<dim3(8, 256), 256, 0, stream>>>(bufh0, W2bh, b2b,
                                              ln_pre_g, Ws, Pbuf);
  k_score_fin<<<BS_/256, 256, 0, stream>>>(Pbuf, ln_pre_g, ln_pre_b, Ws, bs, scores);
  k_softmax<<<B_, 256, 0, stream>>>(scores, probs_out);
  k_spect<<<B_, 256, 0, stream>>>(peaks, probs_out, out);
}

// Round 12
// 517.153 us; speedup vs baseline: 1.0355x; 1.0355x over previous
//
#include <hip/hip_runtime.h>
#include <math.h>

#define B_ 16
#define A_ 32
#define G_ 512
#define S_ 4096
#define M_ 8
#define BS_ 65536
#define KC_ 640      // concat K: 512 normed + 100 OH + 28 pad
#define NG_ 1536

typedef _Float16 half8 __attribute__((ext_vector_type(8)));
typedef _Float16 half4v __attribute__((ext_vector_type(4)));
typedef _Float16 half2v __attribute__((ext_vector_type(2)));
typedef float floatx4 __attribute__((ext_vector_type(4)));

typedef const __attribute__((address_space(1))) void* gas_t;
typedef __attribute__((address_space(3))) void* las_t;

// ---------------- helpers ----------------
__device__ __forceinline__ float wave_sum_f(float v){
#pragma unroll
  for (int o = 32; o > 0; o >>= 1) v += __shfl_xor(v, o);
  return v;
}
__device__ __forceinline__ float wave_max_f(float v){
#pragma unroll
  for (int o = 32; o > 0; o >>= 1) v = fmaxf(v, __shfl_xor(v, o));
  return v;
}
__device__ __forceinline__ float sigmoidf_(float x){ return 1.f/(1.f+__expf(-x)); }
__device__ __forceinline__ float tanhf_(float x){ return 1.f - 2.f/(__expf(2.f*x)+1.f); }

// ---------------- K0a: fp32 -> fp16 convert, 3 G*G matrices ----------------
__global__ __launch_bounds__(256) void k_cvt3(const float* __restrict__ s0,
                                              const float* __restrict__ s1,
                                              const float* __restrict__ s2,
                                              _Float16* __restrict__ d){
  const float* s = (blockIdx.y == 0) ? s0 : (blockIdx.y == 1) ? s1 : s2;
  int i = (blockIdx.x*256 + threadIdx.x)*4;
  if (i >= G_*G_) return;
  float4 v = *(const float4*)(s+i);
  half4v o; o[0]=(_Float16)v.x; o[1]=(_Float16)v.y; o[2]=(_Float16)v.z; o[3]=(_Float16)v.w;
  *(half4v*)(d + (size_t)blockIdx.y*G_*G_ + i) = o;
}

// ---------------- K0b: build Wcat[1536][640] = [W_hh | W_ih | 0] ------------
__global__ __launch_bounds__(64) void k_buildw(const float* __restrict__ Whh,
                                               const float* __restrict__ Wih,
                                               _Float16* __restrict__ Wcat){
  int j = blockIdx.x;
  for (int p = threadIdx.x; p < KC_; p += 64){
    float v = 0.f;
    if (p < 512) v = Whh[(size_t)j*512 + p];
    else if (p < 612) v = Wih[(size_t)j*100 + (p - 512)];
    Wcat[(size_t)j*KC_ + p] = (_Float16)v;
  }
}

// ---------------- K1: MFMA prep — swvs GEMM + LN + counts + OH --------------
__global__ __launch_bounds__(256) void k_prep_mfma(
    const float* __restrict__ vf, const float* __restrict__ mask,
    const float* __restrict__ eoh, const float* __restrict__ subs,
    const float* __restrict__ ln_g, const float* __restrict__ ln_b,
    _Float16* __restrict__ Abuf){
  __shared__ _Float16 s_mvfT[G_*A_];   // [g][a], masked vf, 32 KB
  __shared__ _Float16 s_sm[128*A_];    // [s][a], raw subs, 8 KB
  __shared__ float s_m[A_];
  __shared__ float s_e[A_*5];
  __shared__ float s_ssum[128];
  __shared__ float s_red1[2][4][16];
  __shared__ float s_red2[2][4][16];
  int tid = threadIdx.x;
  int bx = blockIdx.x, b = blockIdx.y;
  int lane = tid & 63, w = tid >> 6;
  int q = lane >> 4, l15 = lane & 15;
  size_t row0 = (size_t)b*S_ + (size_t)bx*128;
  if (tid < A_)   s_m[tid] = mask[b*A_ + tid];
  if (tid < A_*5) s_e[tid] = eoh[b*A_*5 + tid];
  __syncthreads();
  {
    int p = tid & 15, gseg = tid >> 4;
    float mk0 = s_m[2*p], mk1 = s_m[2*p+1];
    const float* v0 = vf + ((size_t)b*A_ + 2*p)*G_ + gseg*32;
    const float* v1 = v0 + G_;
#pragma unroll
    for (int i = 0; i < 32; i += 4){
      float4 a = *(const float4*)(v0 + i);
      float4 c = *(const float4*)(v1 + i);
      float av[4] = {a.x, a.y, a.z, a.w};
      float cv[4] = {c.x, c.y, c.z, c.w};
#pragma unroll
      for (int j = 0; j < 4; ++j){
        half2v h; h[0] = (_Float16)(av[j]*mk0); h[1] = (_Float16)(cv[j]*mk1);
        *(half2v*)(s_mvfT + (gseg*32 + i + j)*A_ + 2*p) = h;
      }
    }
  }
  {
    int s = tid >> 1, hh = tid & 1;
    const float* sp = subs + (row0 + s)*A_ + hh*16;
    _Float16* dst = s_sm + s*A_ + hh*16;
#pragma unroll
    for (int i = 0; i < 16; i += 4){
      float4 v = *(const float4*)(sp + i);
      half4v h; h[0]=(_Float16)v.x; h[1]=(_Float16)v.y; h[2]=(_Float16)v.z; h[3]=(_Float16)v.w;
      *(half4v*)(dst + i) = h;
    }
  }
  __syncthreads();
  if (tid < 128){
    int s = tid;
    float ssum = 0.f, c0=0.f, c1=0.f, c2=0.f, c3=0.f, c4=0.f;
#pragma unroll
    for (int a = 0; a < A_; ++a){
      float v = (float)s_sm[s*A_ + a];
      ssum += v * s_m[a];
      c0 += v * s_e[a*5+0]; c1 += v * s_e[a*5+1]; c2 += v * s_e[a*5+2];
      c3 += v * s_e[a*5+3]; c4 += v * s_e[a*5+4];
    }
    int cc[5];
    cc[0] = min(max((int)(c0+0.5f),0),19); cc[1] = min(max((int)(c1+0.5f),0),19);
    cc[2] = min(max((int)(c2+0.5f),0),19); cc[3] = min(max((int)(c3+0.5f),0),19);
    cc[4] = min(max((int)(c4+0.5f),0),19);
    s_ssum[s] = ssum;
    _Float16* dst = Abuf + (row0 + s)*KC_ + 512;
#pragma unroll
    for (int t = 0; t < 16; ++t){
      half8 hv;
#pragma unroll
      for (int u = 0; u < 8; ++u){
        int k = t*8 + u;
        float v = 0.f;
        if (k < 100){ int f = k/20, l = k - f*20; v = (l <= cc[f]) ? 1.f : 0.f; }
        hv[u] = (_Float16)v;
      }
      *(half8*)(dst + t*8) = hv;
    }
  }
  half8 bf[8]; float lng[8], lnb[8];
#pragma unroll
  for (int t = 0; t < 8; ++t){
    int g = w*128 + t*16 + l15;
    bf[t] = *(const half8*)(s_mvfT + g*A_ + q*8);
    lng[t] = ln_g[g]; lnb[t] = ln_b[g];
  }
  __syncthreads();
  for (int gi = 0; gi < 8; ++gi){
    half8 af = *(const half8*)(s_sm + (gi*16 + l15)*A_ + q*8);
    floatx4 c[8];
#pragma unroll
    for (int t = 0; t < 8; ++t){
      floatx4 z = {0.f, 0.f, 0.f, 0.f};
      c[t] = __builtin_amdgcn_mfma_f32_16x16x32_f16(af, bf[t], z, 0, 0, 0);
    }
    float p1[4] = {0.f,0.f,0.f,0.f}, p2[4] = {0.f,0.f,0.f,0.f};
#pragma unroll
    for (int t = 0; t < 8; ++t)
#pragma unroll
      for (int r = 0; r < 4; ++r){ float v = c[t][r]; p1[r] += v; p2[r] += v*v; }
#pragma unroll
    for (int off = 1; off < 16; off <<= 1)
#pragma unroll
      for (int r = 0; r < 4; ++r){
        p1[r] += __shfl_xor(p1[r], off);
        p2[r] += __shfl_xor(p2[r], off);
      }
    int gb = gi & 1;
    if (l15 == 0){
#pragma unroll
      for (int r = 0; r < 4; ++r){ s_red1[gb][w][q*4+r] = p1[r]; s_red2[gb][w][q*4+r] = p2[r]; }
    }
    __syncthreads();
#pragma unroll
    for (int r = 0; r < 4; ++r){
      int sl = gi*16 + q*4 + r;
      int rr = q*4 + r;
      float t1 = s_red1[gb][0][rr] + s_red1[gb][1][rr] + s_red1[gb][2][rr] + s_red1[gb][3][rr];
      float t2 = s_red2[gb][0][rr] + s_red2[gb][1][rr] + s_red2[gb][2][rr] + s_red2[gb][3][rr];
      float inv = 1.f/(s_ssum[sl] + 1e-4f);
      float mu = t1*inv*(1.f/512.f);
      float var = t2*inv*inv*(1.f/512.f) - mu*mu;
      float rs = rsqrtf(var + 1e-5f);
      _Float16* orow = Abuf + (row0 + sl)*KC_;
#pragma unroll
      for (int t = 0; t < 8; ++t){
        float o = (c[t][r]*inv - mu)*rs*lng[t] + lnb[t];
        orow[w*128 + t*16 + l15] = (_Float16)o;
      }
    }
  }
}

// ---------------- K2: fused (gh+gi) GEMM (3 gates) + GRU elementwise --------
__global__ __launch_bounds__(512) void k_gru_fused(
    const _Float16* __restrict__ Abuf, const _Float16* __restrict__ Wcat,
    const float* __restrict__ bih, const float* __restrict__ bhh,
    _Float16* __restrict__ H){
  __shared__ _Float16 smA[128*32];   // 8 KB
  __shared__ _Float16 smB[192*32];   // 12 KB
  int tid = threadIdx.x;
  int lane = tid & 63, wvid = tid >> 6;      // 8 waves
  int wm = wvid & 1, wn = wvid >> 1;
  int q = lane >> 4, l15 = lane & 15;
  int mt = blockIdx.x*64 + (blockIdx.y >> 3);
  int dt = blockIdx.y & 7;
  int m0 = mt*128, n0 = dt*64;
  floatx4 acc[3][4] = {};
  floatx4 accNI[4] = {};
  int offA[4], offB[3];
#pragma unroll
  for (int i = 0; i < 4; ++i){
    int r = wm*64 + i*16 + l15;
    offA[i] = (r*4 + (q ^ ((r>>2)&3)))*8;
  }
#pragma unroll
  for (int g = 0; g < 3; ++g){
    int rb = g*64 + wn*16 + l15;
    offB[g] = (rb*4 + (q ^ ((rb>>2)&3)))*8;
  }
  const _Float16* gA;
  {
    int u = wvid*64 + lane;
    int r = u >> 2, c = (u & 3) ^ ((r >> 2) & 3);
    gA = Abuf + (size_t)(m0 + r)*KC_ + c*8;
  }
  const _Float16* gB0;
  {
    int u = wvid*64 + lane;
    int rb = u >> 2, c = (u & 3) ^ ((rb >> 2) & 3);
    int grow = (rb >> 6)*512 + n0 + (rb & 63);
    gB0 = Wcat + (size_t)grow*KC_ + c*8;
  }
  const _Float16* gB1 = nullptr;
  if (wvid < 4){
    int u = (8 + wvid)*64 + lane;
    int rb = u >> 2, c = (u & 3) ^ ((rb >> 2) & 3);
    int grow = (rb >> 6)*512 + n0 + (rb & 63);
    gB1 = Wcat + (size_t)grow*KC_ + c*8;
  }
  for (int kc = 0; kc < 512; kc += 32){
    __builtin_amdgcn_global_load_lds((gas_t)(gA + kc), (las_t)(smA + wvid*512), 16, 0, 0);
    __builtin_amdgcn_global_load_lds((gas_t)(gB0 + kc), (las_t)(smB + wvid*512), 16, 0, 0);
    if (wvid < 4)
      __builtin_amdgcn_global_load_lds((gas_t)(gB1 + kc), (las_t)(smB + (8+wvid)*512), 16, 0, 0);
    __syncthreads();
    half8 af[4], bfv[3];
#pragma unroll
    for (int i = 0; i < 4; ++i) af[i] = *(const half8*)(smA + offA[i]);
#pragma unroll
    for (int g = 0; g < 3; ++g) bfv[g] = *(const half8*)(smB + offB[g]);
#pragma unroll
    for (int g = 0; g < 3; ++g)
#pragma unroll
      for (int i = 0; i < 4; ++i)
        acc[g][i] = __builtin_amdgcn_mfma_f32_16x16x32_f16(af[i], bfv[g], acc[g][i], 0, 0, 0);
    __syncthreads();
  }
  for (int kc = 512; kc < KC_; kc += 32){
    __builtin_amdgcn_global_load_lds((gas_t)(gA + kc), (las_t)(smA + wvid*512), 16, 0, 0);
    __builtin_amdgcn_global_load_lds((gas_t)(gB0 + kc), (las_t)(smB + wvid*512), 16, 0, 0);
    if (wvid < 4)
      __builtin_amdgcn_global_load_lds((gas_t)(gB1 + kc), (las_t)(smB + (8+wvid)*512), 16, 0, 0);
    __syncthreads();
    half8 af[4], bfv[3];
#pragma unroll
    for (int i = 0; i < 4; ++i) af[i] = *(const half8*)(smA + offA[i]);
#pragma unroll
    for (int g = 0; g < 3; ++g) bfv[g] = *(const half8*)(smB + offB[g]);
#pragma unroll
    for (int i = 0; i < 4; ++i){
      acc[0][i] = __builtin_amdgcn_mfma_f32_16x16x32_f16(af[i], bfv[0], acc[0][i], 0, 0, 0);
      acc[1][i] = __builtin_amdgcn_mfma_f32_16x16x32_f16(af[i], bfv[1], acc[1][i], 0, 0, 0);
      accNI[i]  = __builtin_amdgcn_mfma_f32_16x16x32_f16(af[i], bfv[2], accNI[i], 0, 0, 0);
    }
    __syncthreads();
  }
  int d = n0 + wn*16 + l15;
  float br  = bih[d] + bhh[d];
  float bz  = bih[512+d] + bhh[512+d];
  float bnh = bhh[1024+d];
  float bni = bih[1024+d];
#pragma unroll
  for (int i = 0; i < 4; ++i){
#pragma unroll
    for (int r = 0; r < 4; ++r){
      int m = m0 + wm*64 + i*16 + q*4 + r;
      float gr  = acc[0][i][r] + br;
      float gz  = acc[1][i][r] + bz;
      float hn  = acc[2][i][r] + bnh;
      float in_ = accNI[i][r] + bni;
      float rrv = sigmoidf_(gr);
      float zz  = sigmoidf_(gz);
      float nn  = tanhf_(in_ + rrv*hn);
      float hp  = (float)Abuf[(size_t)m*KC_ + d];
      H[(size_t)m*G_ + d] = (_Float16)((1.f-zz)*nn + zz*hp);
    }
  }
}

// ---------------- K3: FF fp16 MFMA GEMM (BK=32)  Out = relu(A@W^T+b) --------
// K=512, N=512. grid (8, 256): xcd=bx; mt = bx*64 + (by>>2), nt = by&3.
__global__ __launch_bounds__(256) void k_gemm(
    const _Float16* __restrict__ A, const _Float16* __restrict__ W,
    const float* __restrict__ bias, _Float16* __restrict__ Out){
  __shared__ _Float16 smA[128*32];
  __shared__ _Float16 smB[128*32];
  int tid = threadIdx.x;
  int lane = tid & 63, wvid = tid >> 6;
  int wm = wvid & 1, wn = wvid >> 1;
  int q = lane >> 4, l15 = lane & 15;
  int mt = blockIdx.x*64 + (blockIdx.y >> 2);
  int nt = blockIdx.y & 3;
  int m0 = mt*128, n0 = nt*128;
  floatx4 acc[4][4] = {};
  int offA[4], offB[4];
#pragma unroll
  for (int i = 0; i < 4; ++i){
    int r = wm*64 + i*16 + l15;
    offA[i] = (r*4 + (q ^ ((r>>2)&3)))*8;
    int rb = wn*64 + i*16 + l15;
    offB[i] = (rb*4 + (q ^ ((rb>>2)&3)))*8;
  }
  int uA[2];
  const _Float16 *gA[2], *gB[2];
#pragma unroll
  for (int t = 0; t < 2; ++t){
    int seg = wvid*2 + t;
    int u = seg*64 + lane;
    int r = u >> 2, c = (u & 3) ^ ((r >> 2) & 3);
    uA[t] = seg;
    gA[t] = A + (size_t)(m0 + r)*G_ + c*8;
    gB[t] = W + (size_t)(n0 + r)*G_ + c*8;
  }
  for (int kc = 0; kc < G_; kc += 32){
#pragma unroll
    for (int t = 0; t < 2; ++t){
      __builtin_amdgcn_global_load_lds((gas_t)(gA[t] + kc), (las_t)(smA + uA[t]*512), 16, 0, 0);
      __builtin_amdgcn_global_load_lds((gas_t)(gB[t] + kc), (las_t)(smB + uA[t]*512), 16, 0, 0);
    }
    __syncthreads();
    half8 af[4], bfv[4];
#pragma unroll
    for (int i = 0; i < 4; ++i) af[i] = *(const half8*)(smA + offA[i]);
#pragma unroll
    for (int j = 0; j < 4; ++j) bfv[j] = *(const half8*)(smB + offB[j]);
#pragma unroll
    for (int i = 0; i < 4; ++i)
#pragma unroll
      for (int j = 0; j < 4; ++j)
        acc[i][j] = __builtin_amdgcn_mfma_f32_16x16x32_f16(af[i], bfv[j], acc[i][j], 0, 0, 0);
    __syncthreads();
  }
#pragma unroll
  for (int j = 0; j < 4; ++j){
    int n = n0 + wn*64 + j*16 + l15;
    float bv = bias[n];
#pragma unroll
    for (int i = 0; i < 4; ++i){
#pragma unroll
      for (int r = 0; r < 4; ++r){
        int m = m0 + wm*64 + i*16 + q*4 + r;
        Out[(size_t)m*G_ + n] = (_Float16)fmaxf(acc[i][j][r] + bv, 0.f);
      }
    }
  }
}

// ---------------- K3b: FF3 GEMM (BK=32) + LN/score partials -----------------
// Same K-loop as k_gemm; epilogue emits per-row partials P1=Σx, P2=Σx²,
// P3=Σ(g·Ws)·x over this block's 128 cols -> Pbuf[m][nt][3]. x3 never stored.
__global__ __launch_bounds__(256) void k_ff3_fin(
    const _Float16* __restrict__ A, const _Float16* __restrict__ W,
    const float* __restrict__ bias, const float* __restrict__ ln_pre_g,
    const float* __restrict__ Ws, float* __restrict__ Pbuf){
  __shared__ _Float16 smA[128*32];
  __shared__ _Float16 smB[128*32];
  __shared__ float sP[2][64][2][3];
  int tid = threadIdx.x;
  int lane = tid & 63, wvid = tid >> 6;
  int wm = wvid & 1, wn = wvid >> 1;
  int q = lane >> 4, l15 = lane & 15;
  int mt = blockIdx.x*64 + (blockIdx.y >> 2);
  int nt = blockIdx.y & 3;
  int m0 = mt*128, n0 = nt*128;
  floatx4 acc[4][4] = {};
  int offA[4], offB[4];
#pragma unroll
  for (int i = 0; i < 4; ++i){
    int r = wm*64 + i*16 + l15;
    offA[i] = (r*4 + (q ^ ((r>>2)&3)))*8;
    int rb = wn*64 + i*16 + l15;
    offB[i] = (rb*4 + (q ^ ((rb>>2)&3)))*8;
  }
  int uA[2];
  const _Float16 *gA[2], *gB[2];
#pragma unroll
  for (int t = 0; t < 2; ++t){
    int seg = wvid*2 + t;
    int u = seg*64 + lane;
    int r = u >> 2, c = (u & 3) ^ ((r >> 2) & 3);
    uA[t] = seg;
    gA[t] = A + (size_t)(m0 + r)*G_ + c*8;
    gB[t] = W + (size_t)(n0 + r)*G_ + c*8;
  }
  for (int kc = 0; kc < G_; kc += 32){
#pragma unroll
    for (int t = 0; t < 2; ++t){
      __builtin_amdgcn_global_load_lds((gas_t)(gA[t] + kc), (las_t)(smA + uA[t]*512), 16, 0, 0);
      __builtin_amdgcn_global_load_lds((gas_t)(gB[t] + kc), (las_t)(smB + uA[t]*512), 16, 0, 0);
    }
    __syncthreads();
    half8 af[4], bfv[4];
#pragma unroll
    for (int i = 0; i < 4; ++i) af[i] = *(const half8*)(smA + offA[i]);
#pragma unroll
    for (int j = 0; j < 4; ++j) bfv[j] = *(const half8*)(smB + offB[j]);
#pragma unroll
    for (int i = 0; i < 4; ++i)
#pragma unroll
      for (int j = 0; j < 4; ++j)
        acc[i][j] = __builtin_amdgcn_mfma_f32_16x16x32_f16(af[i], bfv[j], acc[i][j], 0, 0, 0);
    __syncthreads();
  }
  float gws[4], bv4[4];
#pragma unroll
  for (int j = 0; j < 4; ++j){
    int n = n0 + wn*64 + j*16 + l15;
    gws[j] = ln_pre_g[n]*Ws[n];
    bv4[j] = bias[n];
  }
#pragma unroll
  for (int i = 0; i < 4; ++i){
#pragma unroll
    for (int r = 0; r < 4; ++r){
      float p1 = 0.f, p2 = 0.f, p3 = 0.f;
#pragma unroll
      for (int j = 0; j < 4; ++j){
        float x = fmaxf(acc[i][j][r] + bv4[j], 0.f);
        p1 += x; p2 += x*x; p3 += gws[j]*x;
      }
#pragma unroll
      for (int off = 1; off < 16; off <<= 1){
        p1 += __shfl_xor(p1, off);
        p2 += __shfl_xor(p2, off);
        p3 += __shfl_xor(p3, off);
      }
      if (l15 == 0){
        int rl = i*16 + q*4 + r;
        sP[wm][rl][wn][0] = p1; sP[wm][rl][wn][1] = p2; sP[wm][rl][wn][2] = p3;
      }
    }
  }
  __syncthreads();
  if (tid < 128){
    int wmi = tid >> 6, rl = tid & 63;
    int m = m0 + wmi*64 + rl;
    float* dst = Pbuf + ((size_t)m*4 + nt)*3;
    dst[0] = sP[wmi][rl][0][0] + sP[wmi][rl][1][0];
    dst[1] = sP[wmi][rl][0][1] + sP[wmi][rl][1][1];
    dst[2] = sP[wmi][rl][0][2] + sP[wmi][rl][1][2];
  }
}

// ---------------- K4: finish scores from partials ---------------------------
// score = rs*(P3 - mu*C1) + C2 + bs, C1=Σ g·Ws, C2=Σ b·Ws.
__global__ __launch_bounds__(256) void k_score_fin(
    const float* __restrict__ Pbuf, const float* __restrict__ g,
    const float* __restrict__ bta, const float* __restrict__ Ws,
    const float* __restrict__ bs, float* __restrict__ scores){
  __shared__ float red[8];
  int tid = threadIdx.x, lane = tid & 63, wv = tid >> 6;
  int i0 = tid*2;
  float c1p = g[i0]*Ws[i0] + g[i0+1]*Ws[i0+1];
  float c2p = bta[i0]*Ws[i0] + bta[i0+1]*Ws[i0+1];
  c1p = wave_sum_f(c1p); c2p = wave_sum_f(c2p);
  if (lane == 0){ red[wv] = c1p; red[4+wv] = c2p; }
  __syncthreads();
  float c1 = red[0]+red[1]+red[2]+red[3];
  float c2 = red[4]+red[5]+red[6]+red[7] + bs[0];
  size_t row = (size_t)blockIdx.x*256 + tid;
  const float* p = Pbuf + row*12;
  float4 a  = *(const float4*)p;
  float4 b4 = *(const float4*)(p+4);
  float4 c4 = *(const float4*)(p+8);
  float P1 = a.x + a.w + b4.z + c4.y;
  float P2 = a.y + b4.x + b4.w + c4.z;
  float P3 = a.z + b4.y + c4.x + c4.w;
  float mu = P1*(1.f/512.f);
  float var = P2*(1.f/512.f) - mu*mu;
  float rs = rsqrtf(var + 1e-5f);
  scores[row] = rs*(P3 - mu*c1) + c2;
}

// ---------------- K5: softmax over S per batch ------------------------------
__global__ __launch_bounds__(256) void k_softmax(
    const float* __restrict__ scores, float* __restrict__ probs){
  __shared__ float red[4];
  int b = blockIdx.x, tid = threadIdx.x, lane = tid & 63, wv = tid >> 6;
  const float* sp = scores + (size_t)b*S_;
  float mx = -1e30f;
  for (int i = tid; i < S_; i += 256) mx = fmaxf(mx, sp[i]);
  mx = wave_max_f(mx);
  if (lane == 0) red[wv] = mx;
  __syncthreads();
  mx = fmaxf(fmaxf(red[0], red[1]), fmaxf(red[2], red[3]));
  __syncthreads();
  float sum = 0.f;
  for (int i = tid; i < S_; i += 256) sum += __expf(sp[i]-mx);
  sum = wave_sum_f(sum);
  if (lane == 0) red[wv] = sum;
  __syncthreads();
  sum = red[0]+red[1]+red[2]+red[3];
  float inv = 1.f/sum;
  for (int i = tid; i < S_; i += 256)
    probs[(size_t)b*S_ + i] = __expf(sp[i]-mx)*inv;
}

// ---------------- K6: spectrum scatter --------------------------------------
__global__ __launch_bounds__(256) void k_spect(
    const float* __restrict__ peaks, const float* __restrict__ probs,
    float* __restrict__ spect){
  __shared__ float bins[512];
  int b = blockIdx.x, tid = threadIdx.x;
  bins[tid] = 0.f; bins[tid+256] = 0.f;
  __syncthreads();
  for (int i = tid; i < S_*M_; i += 256){
    int s = i >> 3, m = i & 7;
    const float* pk = peaks + (((size_t)b*S_ + s)*M_ + m)*2;
    float mass = pk[0], inten = pk[1];
    float p = probs[(size_t)b*S_ + s];
    int bin = (int)rintf(mass);
    bin = min(max(bin, 0), 511);
    atomicAdd(&bins[bin], inten*p);
  }
  __syncthreads();
  spect[(size_t)b*512 + tid]       = bins[tid];
  spect[(size_t)b*512 + tid + 256] = bins[tid+256];
}

// ---------------- launcher --------------------------------------------------
extern "C" void kernel_launch(void* const* d_in, const int* in_sizes, int n_in,
                              void* d_out, int out_size, void* d_ws, size_t ws_size,
                              hipStream_t stream) {
  const float* vf       = (const float*)d_in[0];
  const float* mask     = (const float*)d_in[1];
  const float* eoh      = (const float*)d_in[2];
  const float* subs     = (const float*)d_in[4];
  const float* peaks    = (const float*)d_in[5];
  const float* ln_sub_g = (const float*)d_in[6];
  const float* ln_sub_b = (const float*)d_in[7];
  const float* W_ih     = (const float*)d_in[8];
  const float* W_hh     = (const float*)d_in[9];
  const float* b_ih     = (const float*)d_in[10];
  const float* b_hh     = (const float*)d_in[11];
  const float* W1       = (const float*)d_in[12];
  const float* b1       = (const float*)d_in[13];
  const float* W2a      = (const float*)d_in[14];
  const float* b2a      = (const float*)d_in[15];
  const float* W2b      = (const float*)d_in[16];
  const float* b2b      = (const float*)d_in[17];
  const float* ln_pre_g = (const float*)d_in[18];
  const float* ln_pre_b = (const float*)d_in[19];
  const float* Ws       = (const float*)d_in[20];
  const float* bs       = (const float*)d_in[21];
  float* out = (float*)d_out;            // [0,8192) spect, [8192,73728) probs
  float* probs_out = out + (size_t)B_*512;

  // workspace carve — ~158 MB (ws >= ~206 MB proven)
  char* w = (char*)d_ws;
  float* scores = (float*)w;     w += (size_t)BS_*4;
  float* Pbuf   = (float*)w;     w += (size_t)BS_*12*4;        // 3 MB
  _Float16* Wcat = (_Float16*)w; w += (size_t)NG_*KC_*2;       // ~2 MB
  _Float16* W1h  = (_Float16*)w; w += (size_t)G_*G_*2;
  _Float16* W2ah = (_Float16*)w; w += (size_t)G_*G_*2;
  _Float16* W2bh = (_Float16*)w; w += (size_t)G_*G_*2;
  _Float16* Abuf = (_Float16*)w; w += (size_t)BS_*KC_*2;       // 84 MB
  _Float16* bufh0 = (_Float16*)w;                              // 67 MB (H)
  _Float16* bufh1 = Abuf;        // x1 reuses A region (84 >= 67 MB)

  k_cvt3<<<dim3((G_*G_/4+255)/256, 3), 256, 0, stream>>>(W1, W2a, W2b, W1h);
  k_buildw<<<NG_, 64, 0, stream>>>(W_hh, W_ih, Wcat);
  k_prep_mfma<<<dim3(S_/128, B_), 256, 0, stream>>>(vf, mask, eoh, subs,
                                                    ln_sub_g, ln_sub_b, Abuf);
  k_gru_fused<<<dim3(8, 512), 512, 0, stream>>>(Abuf, Wcat, b_ih, b_hh, bufh0);
  k_gemm<<<dim3(8, 256), 256, 0, stream>>>(bufh0, W1h,  b1,  bufh1);   // x1
  k_gemm<<<dim3(8, 256), 256, 0, stream>>>(bufh1, W2ah, b2a, bufh0);   // x2
  k_ff3_fin<<<dim3(8, 256), 256, 0, stream>>>(bufh0, W2bh, b2b,
                                              ln_pre_g, Ws, Pbuf);
  k_score_fin<<<BS_/256, 256, 0, stream>>>(Pbuf, ln_pre_g, ln_pre_b, Ws, bs, scores);
  k_softmax<<<B_, 256, 0, stream>>>(scores, probs_out);
  k_spect<<<B_, 256, 0, stream>>>(peaks, probs_out, out);
}